// Round 7
// baseline (84.758 us; speedup 1.0000x reference)
//
#include <hip/hip_runtime.h>
#include <hip/hip_bf16.h>
#include <math.h>

#define NB   2048
#define NC   1000
#define DDIM 128
#define LDT  136      // LDS row stride in bf16 (+8 pad; 272 B rows keep 16B align)
#define NPB  136      // compact triangular proto blocks (by<=bx<16)

typedef __attribute__((ext_vector_type(8))) short  short8;
typedef __attribute__((ext_vector_type(4))) float  floatx4;

__device__ __forceinline__ float bf2f(unsigned short b) {
    union { float f; unsigned int u; } v; v.u = ((unsigned int)b) << 16;
    return v.f;
}

// stage 64 rows x 128 k of fp32 -> bf16 LDS tile (RNE), coalesced float4 reads
__device__ __forceinline__ void stage_cvt(const float* __restrict__ src, int row0, int clampr,
                                          unsigned short* __restrict__ lds, int t) {
    #pragma unroll
    for (int i = 0; i < 8; ++i) {
        int c = (i * 256 + t) * 4;
        int r = c >> 7, k = c & 127;
        int gr = row0 + r; if (gr > clampr) gr = clampr;
        float4 v = *(const float4*)(src + gr * DDIM + k);
        union { __hip_bfloat162 h; unsigned int u; } p0, p1;
        p0.h = __float22bfloat162_rn(make_float2(v.x, v.y));
        p1.h = __float22bfloat162_rn(make_float2(v.z, v.w));
        uint2 st; st.x = p0.u; st.y = p1.u;
        *(uint2*)(lds + r * LDT + k) = st;
    }
}

// per-row squared norms of the ROUNDED bf16 values; 4 lanes per row (64 rows)
__device__ __forceinline__ void norm64(const unsigned short* __restrict__ tile,
                                       float* __restrict__ nrm, int t) {
    int r = t >> 2, seg = t & 3;
    const unsigned short* p = tile + r * LDT + seg * 32;
    float q = 0.0f;
    #pragma unroll
    for (int j = 0; j < 4; ++j) {
        short8 v = *(const short8*)(p + j * 8);
        #pragma unroll
        for (int e = 0; e < 8; ++e) { float f = bf2f((unsigned short)v[e]); q = fmaf(f, f, q); }
    }
    q += __shfl_xor(q, 1);
    q += __shfl_xor(q, 2);
    if (seg == 0) nrm[r] = q;
}

// load 8 contiguous fp32 from a row, convert to bf16 RNE (same value path as stage_cvt)
__device__ __forceinline__ short8 ldfrag(const float* __restrict__ rowp) {
    float4 v0 = *(const float4*)(rowp);
    float4 v1 = *(const float4*)(rowp + 4);
    union { __hip_bfloat162 h; unsigned int u; } a, b, c, d;
    a.h = __float22bfloat162_rn(make_float2(v0.x, v0.y));
    b.h = __float22bfloat162_rn(make_float2(v0.z, v0.w));
    c.h = __float22bfloat162_rn(make_float2(v1.x, v1.y));
    d.h = __float22bfloat162_rn(make_float2(v1.z, v1.w));
    union { unsigned int u[4]; short8 s; } r;
    r.u[0] = a.u; r.u[1] = b.u; r.u[2] = c.u; r.u[3] = d.u;
    return r.s;
}

// ---- proto: compact upper-triangle 64x64 tiles, partial -> ws[bid] (UNCHANGED) ----
__global__ __launch_bounds__(256) void proto_kernel(const float* __restrict__ W,
                                                    float* __restrict__ ws) {
    __shared__ __align__(16) unsigned short As[64 * LDT];
    __shared__ __align__(16) unsigned short Bs[64 * LDT];
    __shared__ float nA[64], nB[64], red[4];
    int bid = blockIdx.x;
    int by = 0, base = 0;                      // map bid -> (by<=bx<16)
    while (base + (16 - by) <= bid) { base += 16 - by; ++by; }
    int bx = by + (bid - base);
    int t = threadIdx.x;
    int row0 = by * 64, col0 = bx * 64;
    stage_cvt(W, row0, NC - 1, As, t);
    stage_cvt(W, col0, NC - 1, Bs, t);
    __syncthreads();
    norm64(As, nA, t);
    norm64(Bs, nB, t);
    int lane = t & 63, w = t >> 6;
    int wm = (w >> 1) * 32, wn = (w & 1) * 32;
    int lm = lane & 15, q = lane >> 4;
    floatx4 acc[2][2] = {{{0,0,0,0},{0,0,0,0}},{{0,0,0,0},{0,0,0,0}}};
    #pragma unroll
    for (int ks = 0; ks < 4; ++ks) {
        int ko = ks * 32 + q * 8;
        short8 a0 = *(const short8*)(As + (wm + lm) * LDT + ko);
        short8 a1 = *(const short8*)(As + (wm + 16 + lm) * LDT + ko);
        short8 b0 = *(const short8*)(Bs + (wn + lm) * LDT + ko);
        short8 b1 = *(const short8*)(Bs + (wn + 16 + lm) * LDT + ko);
        acc[0][0] = __builtin_amdgcn_mfma_f32_16x16x32_bf16(a0, b0, acc[0][0], 0, 0, 0);
        acc[0][1] = __builtin_amdgcn_mfma_f32_16x16x32_bf16(a0, b1, acc[0][1], 0, 0, 0);
        acc[1][0] = __builtin_amdgcn_mfma_f32_16x16x32_bf16(a1, b0, acc[1][0], 0, 0, 0);
        acc[1][1] = __builtin_amdgcn_mfma_f32_16x16x32_bf16(a1, b1, acc[1][1], 0, 0, 0);
    }
    __syncthreads();                           // norms visible
    float local = 0.0f;
    #pragma unroll
    for (int ti = 0; ti < 2; ++ti)
        #pragma unroll
        for (int tj = 0; tj < 2; ++tj) {
            int lc2 = wn + tj * 16 + lm;
            if (col0 + lc2 < NC) {
                float n2 = nB[lc2];
                #pragma unroll
                for (int r = 0; r < 4; ++r) {
                    int lc1 = wm + ti * 16 + q * 4 + r;
                    if (row0 + lc1 < NC) {
                        float d2 = nA[lc1] + n2 - 2.0f * acc[ti][tj][r];
                        local += sqrtf(fmaxf(d2, 0.0f));
                    }
                }
            }
        }
    if (by != bx) local *= 2.0f;               // symmetric double-count
    #pragma unroll
    for (int off = 32; off > 0; off >>= 1) local += __shfl_down(local, off);
    if (lane == 0) red[w] = local;
    __syncthreads();
    if (t == 0) ws[bid] = red[0] + red[1] + red[2] + red[3];
}

// ---- dist: 32x32 tiles, NO LDS staging — fragments & norms direct from global ----
// Critical path: [frag loads + MFMA] || [norms] -> one barrier -> sqrt + store.
__global__ __launch_bounds__(256) void dist_kernel(const float* __restrict__ F,
                                                   const float* __restrict__ W,
                                                   const float* __restrict__ ws,
                                                   float* __restrict__ out) {
    __shared__ float nF[32], nW[32], red2[4];
    int t = threadIdx.x;
    int row0 = blockIdx.y * 32;                // F rows (b), 64 tiles
    int col0 = blockIdx.x * 32;                // W rows (c), 32 tiles

    // proto partials reduce (bit-identical order to baseline)
    float pv = (t < NPB) ? ws[t] : 0.0f;
    #pragma unroll
    for (int off = 32; off > 0; off >>= 1) pv += __shfl_down(pv, off);
    if ((t & 63) == 0) red2[t >> 6] = pv;

    // norms direct from global: threads 0..127 -> F rows, 128..255 -> W rows.
    // Same 4-lane/row split, same RNE-convert -> fmaf order as staged norm64.
    {
        int rr = t >> 2, seg = t & 3;
        const float* gp;
        if (t < 128) {
            int gr = row0 + rr; if (gr > NB - 1) gr = NB - 1;
            gp = F + gr * DDIM + seg * 32;
        } else {
            int gr = col0 + (rr - 32); if (gr > NC - 1) gr = NC - 1;
            gp = W + gr * DDIM + seg * 32;
        }
        float q2 = 0.0f;
        #pragma unroll
        for (int j = 0; j < 4; ++j) {
            short8 v = ldfrag(gp + j * 8);
            #pragma unroll
            for (int e = 0; e < 8; ++e) { float f = bf2f((unsigned short)v[e]); q2 = fmaf(f, f, q2); }
        }
        q2 += __shfl_xor(q2, 1);
        q2 += __shfl_xor(q2, 2);
        if (seg == 0) { if (t < 128) nF[rr] = q2; else nW[rr - 32] = q2; }
    }

    int lane = t & 63, w = t >> 6;
    int lm = lane & 15, q = lane >> 4;
    int wc = (w & 1) * 16;                     // this wave's c sub-tile (m-dim)
    int wb = (w >> 1) * 16;                    // this wave's b sub-tile (n-dim)
    int wr = col0 + wc + lm; if (wr > NC - 1) wr = NC - 1;   // W row (clamped)
    int fr = row0 + wb + lm;                                  // F row (always < NB)
    const float* wp = W + wr * DDIM;
    const float* fp = F + fr * DDIM;
    floatx4 acc = {0, 0, 0, 0};
    #pragma unroll
    for (int ks = 0; ks < 4; ++ks) {
        int ko = ks * 32 + q * 8;
        short8 a = ldfrag(wp + ko);            // A-frag = W (same rounded bits as staged)
        short8 b = ldfrag(fp + ko);            // B-frag = F
        acc = __builtin_amdgcn_mfma_f32_16x16x32_bf16(a, b, acc, 0, 0, 0);
    }
    __syncthreads();                           // norms + red2 visible
    float proto = red2[0] + red2[1] + red2[2] + red2[3];

    int lcb = wc + q * 4;                      // c_local base for this lane
    int cb  = col0 + lcb;                      // global c base (quad-aligned)
    if (cb < NC) {                             // NC%4==0: quad all-or-nothing
        float nw0 = nW[lcb], nw1 = nW[lcb + 1], nw2 = nW[lcb + 2], nw3 = nW[lcb + 3];
        int bg = row0 + wb + lm;               // global F row
        float nb_ = nF[wb + lm];
        float4 o;
        o.x = proto - sqrtf(fmaxf(nw0 + nb_ - 2.0f * acc[0], 0.0f));
        o.y = proto - sqrtf(fmaxf(nw1 + nb_ - 2.0f * acc[1], 0.0f));
        o.z = proto - sqrtf(fmaxf(nw2 + nb_ - 2.0f * acc[2], 0.0f));
        o.w = proto - sqrtf(fmaxf(nw3 + nb_ - 2.0f * acc[3], 0.0f));
        *(float4*)(out + bg * NC + cb) = o;
    }
}

extern "C" void kernel_launch(void* const* d_in, const int* in_sizes, int n_in,
                              void* d_out, int out_size, void* d_ws, size_t ws_size,
                              hipStream_t stream) {
    const float* F  = (const float*)d_in[0];   // (2048,128)
    const float* Wm = (const float*)d_in[1];   // (1000,128)
    float* out = (float*)d_out;                // (2048,1000)
    float* ws  = (float*)d_ws;

    proto_kernel<<<NPB, 256, 0, stream>>>(Wm, ws);                      // 136 partials
    dist_kernel <<<dim3(32, 64), 256, 0, stream>>>(F, Wm, ws, out);     // 2048 tiles
}

// Round 8
// 66.127 us; speedup vs baseline: 1.2818x; 1.2818x over previous
//
#include <hip/hip_runtime.h>
#include <hip/hip_bf16.h>
#include <math.h>

#define NB   2048
#define NC   1000
#define DDIM 128
#define LDT  136      // LDS row stride in bf16 (+8 pad; 272 B rows keep 16B align)
#define NPB  136      // compact triangular proto blocks (by<=bx<16)
#define NFPREP 32     // F prep blocks (64 rows each)
#define NWPREP 16     // W prep blocks (64 rows each)

typedef __attribute__((ext_vector_type(8))) short  short8;
typedef __attribute__((ext_vector_type(4))) float  floatx4;

__device__ __forceinline__ float bf2f(unsigned short b) {
    union { float f; unsigned int u; } v; v.u = ((unsigned int)b) << 16;
    return v.f;
}

// stage 64 rows x 128 k of fp32 -> bf16 LDS tile (RNE), coalesced float4 reads
__device__ __forceinline__ void stage_cvt(const float* __restrict__ src, int row0, int clampr,
                                          unsigned short* __restrict__ lds, int t) {
    #pragma unroll
    for (int i = 0; i < 8; ++i) {
        int c = (i * 256 + t) * 4;
        int r = c >> 7, k = c & 127;
        int gr = row0 + r; if (gr > clampr) gr = clampr;
        float4 v = *(const float4*)(src + gr * DDIM + k);
        union { __hip_bfloat162 h; unsigned int u; } p0, p1;
        p0.h = __float22bfloat162_rn(make_float2(v.x, v.y));
        p1.h = __float22bfloat162_rn(make_float2(v.z, v.w));
        uint2 st; st.x = p0.u; st.y = p1.u;
        *(uint2*)(lds + r * LDT + k) = st;
    }
}

// per-row squared norms of the ROUNDED bf16 values; 4 lanes per row (64 rows)
__device__ __forceinline__ void norm64(const unsigned short* __restrict__ tile,
                                       float* __restrict__ nrm, int t) {
    int r = t >> 2, seg = t & 3;
    const unsigned short* p = tile + r * LDT + seg * 32;
    float q = 0.0f;
    #pragma unroll
    for (int j = 0; j < 4; ++j) {
        short8 v = *(const short8*)(p + j * 8);
        #pragma unroll
        for (int e = 0; e < 8; ++e) { float f = bf2f((unsigned short)v[e]); q = fmaf(f, f, q); }
    }
    q += __shfl_xor(q, 1);
    q += __shfl_xor(q, 2);
    if (seg == 0) nrm[r] = q;
}

// ---- kernel 1: proto tiles (bid<136, byte-identical math) + F/W bf16+norm prep ----
__global__ __launch_bounds__(256) void proto_prep_kernel(const float* __restrict__ F,
                                                         const float* __restrict__ W,
                                                         float* __restrict__ ws,
                                                         unsigned short* __restrict__ Fb,
                                                         unsigned short* __restrict__ Wb,
                                                         float* __restrict__ nFg,
                                                         float* __restrict__ nWg) {
    __shared__ __align__(16) unsigned short As[64 * LDT];
    __shared__ __align__(16) unsigned short Bs[64 * LDT];
    __shared__ float nA[64], nB[64], red[4];
    int bid = blockIdx.x;
    int t = threadIdx.x;

    if (bid >= NPB) {
        // ---------------- prep block: convert 64 rows -> bf16 + per-row norms ----------
        int pb = bid - NPB;
        const float* src; unsigned short* dstb; float* dstn; int row0, clampr, maxrow;
        if (pb < NFPREP) { src = F; dstb = Fb; dstn = nFg; row0 = pb * 64;           clampr = NB - 1; maxrow = NB; }
        else             { src = W; dstb = Wb; dstn = nWg; row0 = (pb - NFPREP) * 64; clampr = NC - 1; maxrow = NC; }
        stage_cvt(src, row0, clampr, As, t);
        __syncthreads();
        norm64(As, nA, t);                     // EXACT same bits as old per-block norms
        __syncthreads();
        #pragma unroll
        for (int i = 0; i < 4; ++i) {          // write bf16 tile (coalesced uint4)
            int idx = i * 256 + t;
            int r = idx >> 4, k = (idx & 15) * 8;
            int gr = row0 + r;
            if (gr < maxrow)
                *(uint4*)(dstb + gr * DDIM + k) = *(const uint4*)(As + r * LDT + k);
        }
        if (t < 64) {
            int gr = row0 + t;
            if (gr < maxrow) dstn[gr] = nA[t];
        }
        return;
    }

    // ---------------- proto tile: compact upper triangle, byte-identical ----------
    int by = 0, base = 0;                      // map bid -> (by<=bx<16)
    while (base + (16 - by) <= bid) { base += 16 - by; ++by; }
    int bx = by + (bid - base);
    int row0 = by * 64, col0 = bx * 64;
    stage_cvt(W, row0, NC - 1, As, t);
    stage_cvt(W, col0, NC - 1, Bs, t);
    __syncthreads();
    norm64(As, nA, t);
    norm64(Bs, nB, t);
    int lane = t & 63, w = t >> 6;
    int wm = (w >> 1) * 32, wn = (w & 1) * 32;
    int lm = lane & 15, q = lane >> 4;
    floatx4 acc[2][2] = {{{0,0,0,0},{0,0,0,0}},{{0,0,0,0},{0,0,0,0}}};
    #pragma unroll
    for (int ks = 0; ks < 4; ++ks) {
        int ko = ks * 32 + q * 8;
        short8 a0 = *(const short8*)(As + (wm + lm) * LDT + ko);
        short8 a1 = *(const short8*)(As + (wm + 16 + lm) * LDT + ko);
        short8 b0 = *(const short8*)(Bs + (wn + lm) * LDT + ko);
        short8 b1 = *(const short8*)(Bs + (wn + 16 + lm) * LDT + ko);
        acc[0][0] = __builtin_amdgcn_mfma_f32_16x16x32_bf16(a0, b0, acc[0][0], 0, 0, 0);
        acc[0][1] = __builtin_amdgcn_mfma_f32_16x16x32_bf16(a0, b1, acc[0][1], 0, 0, 0);
        acc[1][0] = __builtin_amdgcn_mfma_f32_16x16x32_bf16(a1, b0, acc[1][0], 0, 0, 0);
        acc[1][1] = __builtin_amdgcn_mfma_f32_16x16x32_bf16(a1, b1, acc[1][1], 0, 0, 0);
    }
    __syncthreads();                           // norms visible
    float local = 0.0f;
    #pragma unroll
    for (int ti = 0; ti < 2; ++ti)
        #pragma unroll
        for (int tj = 0; tj < 2; ++tj) {
            int lc2 = wn + tj * 16 + lm;
            if (col0 + lc2 < NC) {
                float n2 = nB[lc2];
                #pragma unroll
                for (int r = 0; r < 4; ++r) {
                    int lc1 = wm + ti * 16 + q * 4 + r;
                    if (row0 + lc1 < NC) {
                        float d2 = nA[lc1] + n2 - 2.0f * acc[ti][tj][r];
                        local += sqrtf(fmaxf(d2, 0.0f));
                    }
                }
            }
        }
    if (by != bx) local *= 2.0f;               // symmetric double-count
    #pragma unroll
    for (int off = 32; off > 0; off >>= 1) local += __shfl_down(local, off);
    if (lane == 0) red[w] = local;
    __syncthreads();
    if (t == 0) ws[bid] = red[0] + red[1] + red[2] + red[3];
}

// ---- dist: 64x64 tiles (R0 geometry), bf16 copy-staging, no norm phase, 1 barrier ----
__global__ __launch_bounds__(256) void dist_kernel(const unsigned short* __restrict__ Fb,
                                                   const unsigned short* __restrict__ Wb,
                                                   const float* __restrict__ nFg,
                                                   const float* __restrict__ nWg,
                                                   const float* __restrict__ ws,
                                                   float* __restrict__ out) {
    __shared__ __align__(16) unsigned short Fs[64 * LDT];
    __shared__ __align__(16) unsigned short Ws2[64 * LDT];
    __shared__ float red2[4];
    int t = threadIdx.x;
    int row0 = blockIdx.y * 64;                // F rows (32 tiles)
    int col0 = blockIdx.x * 64;                // W rows (16 tiles)

    float pv = (t < NPB) ? ws[t] : 0.0f;       // proto partials (coalesced 544 B)
    #pragma unroll
    for (int i = 0; i < 4; ++i) {              // copy-stage both bf16 tiles (coalesced uint4)
        int idx = i * 256 + t;
        int r = idx >> 4, k = (idx & 15) * 8;
        int gf = row0 + r;                     // NB = 32*64 exact, no clamp needed
        *(uint4*)(Fs + r * LDT + k) = *(const uint4*)(Fb + gf * DDIM + k);
        int gw = col0 + r; if (gw > NC - 1) gw = NC - 1;
        *(uint4*)(Ws2 + r * LDT + k) = *(const uint4*)(Wb + gw * DDIM + k);
    }
    #pragma unroll
    for (int off = 32; off > 0; off >>= 1) pv += __shfl_down(pv, off);
    if ((t & 63) == 0) red2[t >> 6] = pv;
    __syncthreads();                           // staging + red2 visible (only barrier)
    float proto = red2[0] + red2[1] + red2[2] + red2[3];

    int lane = t & 63, w = t >> 6;
    int wc = (w >> 1) * 32, wb = (w & 1) * 32; // wave offsets: c (m-dim), b (n-dim)
    int lm = lane & 15, q = lane >> 4;
    floatx4 acc[2][2] = {{{0,0,0,0},{0,0,0,0}},{{0,0,0,0},{0,0,0,0}}};
    #pragma unroll
    for (int ks = 0; ks < 4; ++ks) {
        int ko = ks * 32 + q * 8;
        short8 a0 = *(const short8*)(Ws2 + (wc + lm) * LDT + ko);      // A-frag = W
        short8 a1 = *(const short8*)(Ws2 + (wc + 16 + lm) * LDT + ko);
        short8 b0 = *(const short8*)(Fs + (wb + lm) * LDT + ko);       // B-frag = F
        short8 b1 = *(const short8*)(Fs + (wb + 16 + lm) * LDT + ko);
        acc[0][0] = __builtin_amdgcn_mfma_f32_16x16x32_bf16(a0, b0, acc[0][0], 0, 0, 0);
        acc[0][1] = __builtin_amdgcn_mfma_f32_16x16x32_bf16(a0, b1, acc[0][1], 0, 0, 0);
        acc[1][0] = __builtin_amdgcn_mfma_f32_16x16x32_bf16(a1, b0, acc[1][0], 0, 0, 0);
        acc[1][1] = __builtin_amdgcn_mfma_f32_16x16x32_bf16(a1, b1, acc[1][1], 0, 0, 0);
    }

    #pragma unroll
    for (int ci = 0; ci < 2; ++ci) {
        int lcb = wc + ci * 16 + q * 4;        // c_local base for this lane
        int cb  = col0 + lcb;                  // global c base (quad-aligned)
        if (cb < NC) {                         // NC%4==0: quad all-or-nothing
            float4 nw4 = *(const float4*)(nWg + cb);
            float nw0 = nw4.x, nw1 = nw4.y, nw2 = nw4.z, nw3 = nw4.w;
            #pragma unroll
            for (int bj = 0; bj < 2; ++bj) {
                int lb = wb + bj * 16 + lm;
                int bg = row0 + lb;            // global F row
                float nb_ = nFg[bg];
                floatx4 d = acc[ci][bj];
                float4 o;
                o.x = proto - sqrtf(fmaxf(nw0 + nb_ - 2.0f * d[0], 0.0f));
                o.y = proto - sqrtf(fmaxf(nw1 + nb_ - 2.0f * d[1], 0.0f));
                o.z = proto - sqrtf(fmaxf(nw2 + nb_ - 2.0f * d[2], 0.0f));
                o.w = proto - sqrtf(fmaxf(nw3 + nb_ - 2.0f * d[3], 0.0f));
                *(float4*)(out + bg * NC + cb) = o;
            }
        }
    }
}

extern "C" void kernel_launch(void* const* d_in, const int* in_sizes, int n_in,
                              void* d_out, int out_size, void* d_ws, size_t ws_size,
                              hipStream_t stream) {
    const float* F  = (const float*)d_in[0];   // (2048,128)
    const float* Wm = (const float*)d_in[1];   // (1000,128)
    float* out = (float*)d_out;                // (2048,1000)
    float* ws  = (float*)d_ws;

    // workspace layout (floats): [0..135] proto partials; bf16 F at +1024 (512 KB);
    // bf16 W next (256 KB); nF (2048 f32); nW (1000 f32). All 16B-aligned.
    unsigned short* Fb = (unsigned short*)(ws + 1024);
    unsigned short* Wb = Fb + (size_t)NB * DDIM;
    float* nFg = (float*)(Wb + (size_t)NC * DDIM);
    float* nWg = nFg + NB;

    proto_prep_kernel<<<NPB + NFPREP + NWPREP, 256, 0, stream>>>(F, Wm, ws, Fb, Wb, nFg, nWg);
    dist_kernel<<<dim3(16, 32), 256, 0, stream>>>(Fb, Wb, nFg, nWg, ws, out);
}